// Round 7
// baseline (8582.367 us; speedup 1.0000x reference)
//
#include <hip/hip_runtime.h>
#include <hip/hip_bf16.h>
#include <float.h>
#include <math.h>

#define NB 4
#define NN 8192
#define FF 64
#define MM 2048
#define KK 32
#define HH 64

#define FT2 1024        // fps threads (16 waves)
#define SPT 8           // points per thread at setup
#define NG2 128         // groups of 64 sorted points

// 3-wide DPP argmax step: carries (value, orig idx, lds slot); tie -> lower oi.
// identities: v=-inf, oi=INT_MAX, si=0 (never selected). (validated r4/r5/r6)
#define DPP3_STEP(bv, boi, bsi, ctrl, rmask)                                    \
    {                                                                           \
        int _v  = __builtin_amdgcn_update_dpp((int)0xff800000,                  \
                      __float_as_int(bv), (ctrl), (rmask), 0xf, false);         \
        int _oi = __builtin_amdgcn_update_dpp((int)0x7fffffff,                  \
                      (boi), (ctrl), (rmask), 0xf, false);                      \
        int _si = __builtin_amdgcn_update_dpp(0, (bsi), (ctrl), (rmask), 0xf, false); \
        float _vf = __int_as_float(_v);                                         \
        if (_vf > (bv) || (_vf == (bv) && _oi < (boi)))                         \
            { (bv) = _vf; (boi) = _oi; (bsi) = _si; }                           \
    }
#define DPP3_REDUCE(bv, boi, bsi)            \
    DPP3_STEP(bv, boi, bsi, 0x111, 0xf)      \
    DPP3_STEP(bv, boi, bsi, 0x112, 0xf)      \
    DPP3_STEP(bv, boi, bsi, 0x114, 0xf)      \
    DPP3_STEP(bv, boi, bsi, 0x118, 0xf)      \
    DPP3_STEP(bv, boi, bsi, 0x142, 0xa)      \
    DPP3_STEP(bv, boi, bsi, 0x143, 0xc)

#define DPP_FADD(v, ctrl, rmask)                                                \
    { int _t = __builtin_amdgcn_update_dpp(0, __float_as_int(v), (ctrl),        \
                   (rmask), 0xf, false);                                        \
      (v) = __fadd_rn((v), __int_as_float(_t)); }
#define DPP_FMAX(v, ctrl, rmask)                                                \
    { int _t = __builtin_amdgcn_update_dpp((int)0xff800000, __float_as_int(v),  \
                   (ctrl), (rmask), 0xf, false);                                \
      (v) = fmaxf((v), __int_as_float(_t)); }
#define DPP_SUM6(v)  DPP_FADD(v,0x111,0xf) DPP_FADD(v,0x112,0xf) DPP_FADD(v,0x114,0xf) \
                     DPP_FADD(v,0x118,0xf) DPP_FADD(v,0x142,0xa) DPP_FADD(v,0x143,0xc)
#define DPP_MAX6(v)  DPP_FMAX(v,0x111,0xf) DPP_FMAX(v,0x112,0xf) DPP_FMAX(v,0x114,0xf) \
                     DPP_FMAX(v,0x118,0xf) DPP_FMAX(v,0x142,0xa) DPP_FMAX(v,0x143,0xc)

__device__ __forceinline__ int spread3(int v) {
    return (v & 1) | ((v & 2) << 2) | ((v & 4) << 4);
}
__device__ __forceinline__ float readlane_f(float v, int l) {
    return __int_as_float(__builtin_amdgcn_readlane(__float_as_int(v), l));
}

// ------------- Kernel 1: exact FPS, wave-uniform group pruning -------------
__global__ __launch_bounds__(FT2) void fps_kernel(
    const float* __restrict__ pos,
    int* __restrict__ samp,
    float* __restrict__ centers_out,
    float* __restrict__ batch_out)
{
    __shared__ float4 pts4[NN];       // sorted points, .w = orig idx bits (128 KB)
    __shared__ float4 gw[NG2];        // per-group winner (v, oi, slot, 0)
    __shared__ int hist[512];
    __shared__ int off[512];

    const int b = blockIdx.x;
    const float* pb = pos + (size_t)b * NN * 3;
    const int tid = threadIdx.x;
    const int w   = tid >> 6;
    const int lane = tid & 63;

    // ---- setup: load, morton code, counting sort ----
    float px[SPT], py[SPT], pz[SPT];
    int   mt[SPT];
    if (tid < 512) hist[tid] = 0;
    __syncthreads();
#pragma unroll
    for (int i = 0; i < SPT; ++i) {
        const int j = tid + i * FT2;
        px[i] = pb[j * 3 + 0];
        py[i] = pb[j * 3 + 1];
        pz[i] = pb[j * 3 + 2];
        int cx = (int)(px[i] * 8.0f), cy = (int)(py[i] * 8.0f), cz = (int)(pz[i] * 8.0f);
        cx = min(max(cx, 0), 7); cy = min(max(cy, 0), 7); cz = min(max(cz, 0), 7);
        mt[i] = spread3(cx) | (spread3(cy) << 1) | (spread3(cz) << 2);
        atomicAdd(&hist[mt[i]], 1);
    }
    for (int j = tid; j < MM; j += FT2) batch_out[b * MM + j] = (float)b;
    __syncthreads();
    for (int d = 1; d < 512; d <<= 1) {
        int v = 0;
        if (tid < 512) v = hist[tid] + ((tid >= d) ? hist[tid - d] : 0);
        __syncthreads();
        if (tid < 512) hist[tid] = v;
        __syncthreads();
    }
    if (tid < 512) off[tid] = tid ? hist[tid - 1] : 0;
    __syncthreads();
#pragma unroll
    for (int i = 0; i < SPT; ++i) {
        const int slot = atomicAdd(&off[mt[i]], 1);
        pts4[slot] = make_float4(px[i], py[i], pz[i], __int_as_float(tid + i * FT2));
    }
    __syncthreads();

    // ---- per-owned-group metadata in REGISTERS (wave w owns groups w+16j) ----
    float mx[8], my[8], mz[8], mr[8], dist_r[8], gm_r[8];
#pragma unroll
    for (int j = 0; j < 8; ++j) {
        const int g = w + (j << 4);
        const float4 p = pts4[(g << 6) + lane];
        float sx = p.x, sy = p.y, sz = p.z;
        DPP_SUM6(sx) DPP_SUM6(sy) DPP_SUM6(sz)
        const float gx = readlane_f(sx, 63) * (1.0f / 64.0f);
        const float gy = readlane_f(sy, 63) * (1.0f / 64.0f);
        const float gz = readlane_f(sz, 63) * (1.0f / 64.0f);
        const float dx = p.x - gx, dy = p.y - gy, dz = p.z - gz;
        float d2 = dx * dx + dy * dy + dz * dz;
        DPP_MAX6(d2)
        const float r2 = readlane_f(d2, 63);
        mx[j] = gx; my[j] = gy; mz[j] = gz;
        mr[j] = sqrtf(r2) * 1.00005f + 1e-7f;   // conservative upper bound
        dist_r[j] = INFINITY;
        gm_r[j] = INFINITY;                      // inf => never skip before 1st update
        if (lane == 63)
            gw[g] = make_float4(INFINITY, __int_as_float(0x7fffffff),
                                __int_as_float(g << 6), 0.0f);
    }
    __syncthreads();

    int   cur = 0;
    float lx = pb[0], ly = pb[1], lz = pb[2];

    for (int s = 0; s < MM; ++s) {
        if (tid == 0) {
            samp[b * MM + s] = cur;
            centers_out[((size_t)b * MM + s) * 3 + 0] = lx;
            centers_out[((size_t)b * MM + s) * 3 + 1] = ly;
            centers_out[((size_t)b * MM + s) * 3 + 2] = lz;
        }
        if (s == MM - 1) break;

        // ---- phase 2: test + update owned groups (wave-uniform skip) ----
#pragma unroll
        for (int j = 0; j < 8; ++j) {
            const int g = w + (j << 4);
            // LDS-free, lane-uniform prune test (validated margins)
            const float dxc = mx[j] - lx, dyc = my[j] - ly, dzc = mz[j] - lz;
            const float d2c = dxc * dxc + dyc * dyc + dzc * dzc;
            const float t   = __fsub_rn(__fmul_rn(sqrtf(d2c), 0.99999f), mr[j]);
            const bool skip = (t > 0.0f) &&
                              (__fmul_rn(t, t) >= __fmul_rn(gm_r[j], 1.00004f));
            if (!skip) {
                const int slot = (g << 6) + lane;
                const float4 p = pts4[slot];
                // exact ref arithmetic: ((dx*dx + dy*dy) + dz*dz), no FMA
                const float dx = __fsub_rn(p.x, lx);
                const float dy = __fsub_rn(p.y, ly);
                const float dz = __fsub_rn(p.z, lz);
                const float d  = __fadd_rn(__fadd_rn(__fmul_rn(dx, dx),
                                                     __fmul_rn(dy, dy)),
                                           __fmul_rn(dz, dz));
                const float nd = fminf(dist_r[j], d);
                dist_r[j] = nd;
                float bv = nd; int boi = __float_as_int(p.w); int bsi = slot;
                DPP3_REDUCE(bv, boi, bsi)
                gm_r[j] = readlane_f(bv, 63);
                if (lane == 63)
                    gw[g] = make_float4(bv, __int_as_float(boi),
                                        __int_as_float(bsi), 0.0f);
            }
        }
        __syncthreads();   // B1: group winners visible to all waves

        // ---- phase 3: all waves redundantly reduce the 128 group winners ----
        const float4 e0 = gw[lane];
        const float4 e1 = gw[64 + lane];
        float bv = e0.x; int boi = __float_as_int(e0.y); int bsi = __float_as_int(e0.z);
        {
            const float v1 = e1.x;
            const int   o1 = __float_as_int(e1.y), s1i = __float_as_int(e1.z);
            if (v1 > bv || (v1 == bv && o1 < boi)) { bv = v1; boi = o1; bsi = s1i; }
        }
        DPP3_REDUCE(bv, boi, bsi)
        cur = __builtin_amdgcn_readlane(boi, 63);
        const int csi = __builtin_amdgcn_readlane(bsi, 63);
        const float4 wp = pts4[csi];             // broadcast, conflict-free
        lx = wp.x; ly = wp.y; lz = wp.z;
        __syncthreads();   // B2: protect gw reads from next step's writes
    }
}

// ---------------- Kernel 2: radius-KNN, one wave per center ----------------
#define CAP 256
__global__ __launch_bounds__(256) void knn_kernel(
    const float* __restrict__ pos,
    const int* __restrict__ samp,
    int* __restrict__ nbr,
    int* __restrict__ cntbuf)
{
    const int wave = threadIdx.x >> 6;
    const int lane = threadIdx.x & 63;
    const int c = blockIdx.x * 4 + wave;
    const int b = c >> 11;
    const float* pb = pos + (size_t)b * NN * 3;

    __shared__ float sd2[4][CAP];
    __shared__ int   sid[4][CAP];

    const int ctr = samp[c];
    const float cx = pb[ctr * 3 + 0];
    const float cy = pb[ctr * 3 + 1];
    const float cz = pb[ctr * 3 + 2];
    const float R2 = (float)(0.1 * 0.1);

    int cnt = 0;
    for (int r = 0; r < NN / 64; ++r) {
        const int g = r * 64 + lane;
        float dx = __fsub_rn(cx, pb[g * 3 + 0]);
        float dy = __fsub_rn(cy, pb[g * 3 + 1]);
        float dz = __fsub_rn(cz, pb[g * 3 + 2]);
        float d2 = __fadd_rn(__fadd_rn(__fmul_rn(dx, dx), __fmul_rn(dy, dy)),
                             __fmul_rn(dz, dz));
        const bool pred = (d2 <= R2);
        const unsigned long long mask = __ballot(pred);
        const int before = __popcll(mask & ((1ull << lane) - 1ull));
        if (pred) {
            const int slot = cnt + before;
            if (slot < CAP) { sd2[wave][slot] = d2; sid[wave][slot] = g; }
        }
        cnt += __popcll(mask);
    }
    if (cnt > CAP) cnt = CAP;
    __syncthreads();

    for (int ci = lane; ci < cnt; ci += 64) {
        const float dc = sd2[wave][ci];
        const int   ic = sid[wave][ci];
        int rank = 0;
        for (int j = 0; j < cnt; ++j) {
            const float dj = sd2[wave][j];
            const int   ij = sid[wave][j];
            rank += (dj < dc || (dj == dc && ij < ic)) ? 1 : 0;
        }
        if (rank < KK) nbr[c * KK + rank] = ic;
    }
    if (lane == 0) cntbuf[c] = (cnt < KK) ? cnt : KK;
}

// ---------------- Kernel 3: gather + MLP + max-pool, one wave per center ----
__global__ __launch_bounds__(256) void mlp_kernel(
    const float* __restrict__ x,
    const float* __restrict__ pos,
    const float* __restrict__ W1,
    const float* __restrict__ b1,
    const float* __restrict__ W2,
    const float* __restrict__ b2,
    const int* __restrict__ nbr,
    const int* __restrict__ cntbuf,
    const float* __restrict__ centers,
    float* __restrict__ out)
{
    __shared__ float WT[64 * 68];
    __shared__ float featL[4][32 * 68];

    const int tid = threadIdx.x, wave = tid >> 6, lane = tid & 63;
    const int c = blockIdx.x * 4 + wave;
    const int b = c >> 11;
    const int cnt = cntbuf[c];

    for (int idx = tid; idx < 67 * 64; idx += 256) {
        const int i = idx >> 6, h = idx & 63;
        WT[h * 68 + i] = W1[idx];
    }
    if (tid < 64) WT[tid * 68 + 67] = 0.0f;

    const float ctr0 = centers[c * 3 + 0];
    const float ctr1 = centers[c * 3 + 1];
    const float ctr2 = centers[c * 3 + 2];
    for (int k = 0; k < cnt; ++k) {
        const int j = nbr[c * KK + k];
        featL[wave][k * 68 + lane] = x[((size_t)b * NN + j) * FF + lane];
        if (lane < 3) {
            const float pj = pos[((size_t)b * NN + j) * 3 + lane];
            const float ci = (lane == 0) ? ctr0 : ((lane == 1) ? ctr1 : ctr2);
            featL[wave][k * 68 + 64 + lane] = __fsub_rn(pj, ci);
        }
        if (lane == 3) featL[wave][k * 68 + 67] = 0.0f;
    }
    __syncthreads();

    float wreg[68];
#pragma unroll
    for (int i4 = 0; i4 < 17; ++i4) {
        const float4 v = *(const float4*)&WT[lane * 68 + i4 * 4];
        wreg[i4 * 4 + 0] = v.x; wreg[i4 * 4 + 1] = v.y;
        wreg[i4 * 4 + 2] = v.z; wreg[i4 * 4 + 3] = v.w;
    }
    const float bias1 = b1[lane];
    for (int k = 0; k < cnt; ++k) {
        float acc = bias1;
#pragma unroll
        for (int i4 = 0; i4 < 17; ++i4) {
            const float4 f = *(const float4*)&featL[wave][k * 68 + i4 * 4];
            acc = fmaf(f.x, wreg[i4 * 4 + 0], acc);
            acc = fmaf(f.y, wreg[i4 * 4 + 1], acc);
            acc = fmaf(f.z, wreg[i4 * 4 + 2], acc);
            acc = fmaf(f.w, wreg[i4 * 4 + 3], acc);
        }
        featL[wave][k * 68 + lane] = fmaxf(acc, 0.0f);
    }
    __syncthreads();

    for (int idx = tid; idx < 64 * 64; idx += 256) {
        const int i = idx >> 6, h = idx & 63;
        WT[h * 68 + i] = W2[idx];
    }
    __syncthreads();

#pragma unroll
    for (int i4 = 0; i4 < 16; ++i4) {
        const float4 v = *(const float4*)&WT[lane * 68 + i4 * 4];
        wreg[i4 * 4 + 0] = v.x; wreg[i4 * 4 + 1] = v.y;
        wreg[i4 * 4 + 2] = v.z; wreg[i4 * 4 + 3] = v.w;
    }
    const float bias2 = b2[lane];
    float m = -INFINITY;
    for (int k = 0; k < cnt; ++k) {
        float acc = bias2;
#pragma unroll
        for (int i4 = 0; i4 < 16; ++i4) {
            const float4 f = *(const float4*)&featL[wave][k * 68 + i4 * 4];
            acc = fmaf(f.x, wreg[i4 * 4 + 0], acc);
            acc = fmaf(f.y, wreg[i4 * 4 + 1], acc);
            acc = fmaf(f.z, wreg[i4 * 4 + 2], acc);
            acc = fmaf(f.w, wreg[i4 * 4 + 3], acc);
        }
        m = fmaxf(m, fmaxf(acc, 0.0f));
    }
    out[(size_t)c * HH + lane] = (cnt > 0) ? m : 0.0f;
}

extern "C" void kernel_launch(void* const* d_in, const int* in_sizes, int n_in,
                              void* d_out, int out_size, void* d_ws, size_t ws_size,
                              hipStream_t stream) {
    const float* x   = (const float*)d_in[0];
    const float* pos = (const float*)d_in[1];
    const float* W1  = (const float*)d_in[3];
    const float* b1  = (const float*)d_in[4];
    const float* W2  = (const float*)d_in[5];
    const float* b2  = (const float*)d_in[6];

    float* out         = (float*)d_out;
    float* centers_out = out + (size_t)NB * MM * HH;
    float* batch_out   = centers_out + (size_t)NB * MM * 3;

    char* ws = (char*)d_ws;
    int* samp   = (int*)ws;
    int* cntbuf = (int*)(ws + (size_t)NB * MM * 4);
    int* nbr    = (int*)(ws + (size_t)2 * NB * MM * 4);

    fps_kernel<<<NB, FT2, 0, stream>>>(pos, samp, centers_out, batch_out);
    knn_kernel<<<(NB * MM) / 4, 256, 0, stream>>>(pos, samp, nbr, cntbuf);
    mlp_kernel<<<(NB * MM) / 4, 256, 0, stream>>>(x, pos, W1, b1, W2, b2,
                                                  nbr, cntbuf, centers_out, out);
}